// Round 2
// baseline (2305.381 us; speedup 1.0000x reference)
//
#include <hip/hip_runtime.h>
#include <hip/hip_bf16.h>
#include <math.h>

#define BTOT 16384

__device__ __forceinline__ float selu_f(float x) {
  const float scale = 1.0507009873554805f;
  const float alpha = 1.6732632423543772f;
  return scale * (x > 0.0f ? x : alpha * expm1f(x));
}

// Y[b][n] = act( sum_{k<Kc} X[b][k]*W[k][n] + t[b]*W[Kc][n] + bias[n] )
// Tile: BM=128, BN=128, BK=32; 256 threads, 8x8 per thread, fp32.
template<bool DO_SELU>
__global__ __launch_bounds__(256) void mlp_layer_kernel(
    const float* __restrict__ X, int ldx, int Kc,
    const float* __restrict__ tvec,
    const float* __restrict__ W,     // [(Kc+1) x N]
    const float* __restrict__ bias,  // [N]
    float* __restrict__ Y, int N)
{
  __shared__ float sX[128][33];
  __shared__ float sW[32][128];
  const int tid = threadIdx.x;
  const int bm = blockIdx.x, bn = blockIdx.y;
  const int tx = tid & 15, ty = tid >> 4;
  const int rowbase = bm * 128, colbase = bn * 128;

  float acc[8][8];
  #pragma unroll
  for (int i = 0; i < 8; ++i)
    #pragma unroll
    for (int j = 0; j < 8; ++j) acc[i][j] = 0.0f;

  for (int k0 = 0; k0 < Kc; k0 += 32) {
    // load X tile 128x32
    {
      const int r0 = tid >> 3;
      const int kc = (tid & 7) << 2;
      #pragma unroll
      for (int pp = 0; pp < 4; ++pp) {
        int r = r0 + pp * 32;
        float4 v = *reinterpret_cast<const float4*>(
            X + (size_t)(rowbase + r) * ldx + k0 + kc);
        sX[r][kc + 0] = v.x; sX[r][kc + 1] = v.y;
        sX[r][kc + 2] = v.z; sX[r][kc + 3] = v.w;
      }
    }
    // load W tile 32x128
    {
      const int kk0 = tid >> 5;
      const int cc = (tid & 31) << 2;
      #pragma unroll
      for (int pp = 0; pp < 4; ++pp) {
        int kk = kk0 + pp * 8;
        *reinterpret_cast<float4*>(&sW[kk][cc]) =
            *reinterpret_cast<const float4*>(W + (size_t)(k0 + kk) * N + colbase + cc);
      }
    }
    __syncthreads();
    #pragma unroll
    for (int kk = 0; kk < 32; ++kk) {
      float a[8], b[8];
      #pragma unroll
      for (int i = 0; i < 8; ++i) a[i] = sX[ty * 8 + i][kk];
      float4 bv0 = *reinterpret_cast<const float4*>(&sW[kk][tx * 8]);
      float4 bv1 = *reinterpret_cast<const float4*>(&sW[kk][tx * 8 + 4]);
      b[0] = bv0.x; b[1] = bv0.y; b[2] = bv0.z; b[3] = bv0.w;
      b[4] = bv1.x; b[5] = bv1.y; b[6] = bv1.z; b[7] = bv1.w;
      #pragma unroll
      for (int i = 0; i < 8; ++i)
        #pragma unroll
        for (int j = 0; j < 8; ++j) acc[i][j] = fmaf(a[i], b[j], acc[i][j]);
    }
    __syncthreads();
  }

  // epilogue: t-term + bias + act + store
  float4 wl0 = *reinterpret_cast<const float4*>(W + (size_t)Kc * N + colbase + tx * 8);
  float4 wl1 = *reinterpret_cast<const float4*>(W + (size_t)Kc * N + colbase + tx * 8 + 4);
  float4 bb0 = *reinterpret_cast<const float4*>(bias + colbase + tx * 8);
  float4 bb1 = *reinterpret_cast<const float4*>(bias + colbase + tx * 8 + 4);
  float wl[8] = {wl0.x, wl0.y, wl0.z, wl0.w, wl1.x, wl1.y, wl1.z, wl1.w};
  float bb[8] = {bb0.x, bb0.y, bb0.z, bb0.w, bb1.x, bb1.y, bb1.z, bb1.w};
  #pragma unroll
  for (int i = 0; i < 8; ++i) {
    int row = rowbase + ty * 8 + i;
    float tv = tvec[row];
    float o[8];
    #pragma unroll
    for (int j = 0; j < 8; ++j) {
      float v = acc[i][j] + tv * wl[j] + bb[j];
      o[j] = DO_SELU ? selu_f(v) : v;
    }
    float4* dst = reinterpret_cast<float4*>(Y + (size_t)row * N + colbase + tx * 8);
    dst[0] = make_float4(o[0], o[1], o[2], o[3]);
    dst[1] = make_float4(o[4], o[5], o[6], o[7]);
  }
}

// One 32x32 matrix per 32-lane half-wave; lane i owns row i.
// expm via scaling (theta=1.0) + order-8 Taylor + squaring. All in-wave,
// LDS only for row-broadcast; no __syncthreads (avoids divergent barriers).
// NOTE: no runtime-indexed register arrays anywhere (rule #20) — the v1
// kernel's `A[lane]` forced A[] to scratch (4.6 GB FETCH).
__global__ __launch_bounds__(256) void expm_kernel(
    const float* __restrict__ flat,   // [B,1024]
    const float* __restrict__ q,      // [B,32]
    const float* __restrict__ dtp,    // [1]
    float* __restrict__ out_q,        // [B,32]
    float* __restrict__ out_dlogp)    // [B]
{
  __shared__ float S[8][32][32];
  const int tid = threadIdx.x;
  const int g = tid >> 5;
  const int lane = tid & 31;
  const int m = blockIdx.x * 8 + g;
  const float dt = dtp[0];

  float A[32];
  {
    const float* fr = flat + (size_t)m * 1024 + lane * 32;
    #pragma unroll
    for (int j4 = 0; j4 < 8; ++j4) {
      float4 v = *reinterpret_cast<const float4*>(fr + j4 * 4);
      A[j4 * 4 + 0] = dt * fminf(fmaxf(v.x, -20.f), 20.f);
      A[j4 * 4 + 1] = dt * fminf(fmaxf(v.y, -20.f), 20.f);
      A[j4 * 4 + 2] = dt * fminf(fmaxf(v.z, -20.f), 20.f);
      A[j4 * 4 + 3] = dt * fminf(fmaxf(v.w, -20.f), 20.f);
    }
  }

  // dlogp = trace(A): pick own diagonal element WITHOUT dynamic reg indexing
  float tr = 0.0f;
  #pragma unroll
  for (int j = 0; j < 32; ++j) tr += (j == lane) ? A[j] : 0.0f;
  #pragma unroll
  for (int off = 1; off < 32; off <<= 1) tr += __shfl_xor(tr, off);
  if (lane == 0) out_dlogp[m] = tr;

  // stage A in LDS, compute 1-norm (max column abs-sum)
  #pragma unroll
  for (int j4 = 0; j4 < 8; ++j4)
    *reinterpret_cast<float4*>(&S[g][lane][j4 * 4]) =
        make_float4(A[j4 * 4], A[j4 * 4 + 1], A[j4 * 4 + 2], A[j4 * 4 + 3]);
  asm volatile("s_waitcnt lgkmcnt(0)" ::: "memory");
  float cs = 0.f;
  #pragma unroll
  for (int i = 0; i < 32; ++i) cs += fabsf(S[g][i][lane]);
  float nrm = cs;
  #pragma unroll
  for (int off = 1; off < 32; off <<= 1) nrm = fmaxf(nrm, __shfl_xor(nrm, off));

  int s = 0;
  if (nrm > 1.0f) {
    s = (int)ceilf(log2f(nrm));   // scale so ||A/2^s|| <= 1 (order-8 Taylor ok)
    if (s < 0) s = 0;
    if (s > 12) s = 12;
  }
  const float sc = exp2f(-(float)s);
  #pragma unroll
  for (int j = 0; j < 32; ++j) A[j] *= sc;
  #pragma unroll
  for (int j4 = 0; j4 < 8; ++j4)
    *reinterpret_cast<float4*>(&S[g][lane][j4 * 4]) =
        make_float4(A[j4 * 4], A[j4 * 4 + 1], A[j4 * 4 + 2], A[j4 * 4 + 3]);
  asm volatile("s_waitcnt lgkmcnt(0)" ::: "memory");

  // Taylor: E = I + A + A^2/2! + ... + A^8/8!
  float E[32], T[32];
  #pragma unroll
  for (int j = 0; j < 32; ++j) { T[j] = A[j]; E[j] = A[j] + (j == lane ? 1.f : 0.f); }

  #pragma unroll 1
  for (int k = 2; k <= 8; ++k) {   // runtime loop; inner fully unrolled (static reg idx)
    float Tn[32];
    #pragma unroll
    for (int j = 0; j < 32; ++j) Tn[j] = 0.f;
    #pragma unroll
    for (int kk = 0; kk < 32; ++kk) {
      float tv = T[kk];
      #pragma unroll
      for (int j4 = 0; j4 < 8; ++j4) {
        float4 sr = *reinterpret_cast<const float4*>(&S[g][kk][j4 * 4]);
        Tn[j4 * 4 + 0] = fmaf(tv, sr.x, Tn[j4 * 4 + 0]);
        Tn[j4 * 4 + 1] = fmaf(tv, sr.y, Tn[j4 * 4 + 1]);
        Tn[j4 * 4 + 2] = fmaf(tv, sr.z, Tn[j4 * 4 + 2]);
        Tn[j4 * 4 + 3] = fmaf(tv, sr.w, Tn[j4 * 4 + 3]);
      }
    }
    const float inv = 1.0f / (float)k;
    #pragma unroll
    for (int j = 0; j < 32; ++j) { T[j] = Tn[j] * inv; E[j] += T[j]; }
  }

  // squaring: E = E^(2^s)
  #pragma unroll 1
  for (int it = 0; it < s; ++it) {
    #pragma unroll
    for (int j4 = 0; j4 < 8; ++j4)
      *reinterpret_cast<float4*>(&S[g][lane][j4 * 4]) =
          make_float4(E[j4 * 4], E[j4 * 4 + 1], E[j4 * 4 + 2], E[j4 * 4 + 3]);
    asm volatile("s_waitcnt lgkmcnt(0)" ::: "memory");
    float En[32];
    #pragma unroll
    for (int j = 0; j < 32; ++j) En[j] = 0.f;
    #pragma unroll
    for (int kk = 0; kk < 32; ++kk) {
      float ev = E[kk];
      #pragma unroll
      for (int j4 = 0; j4 < 8; ++j4) {
        float4 sr = *reinterpret_cast<const float4*>(&S[g][kk][j4 * 4]);
        En[j4 * 4 + 0] = fmaf(ev, sr.x, En[j4 * 4 + 0]);
        En[j4 * 4 + 1] = fmaf(ev, sr.y, En[j4 * 4 + 1]);
        En[j4 * 4 + 2] = fmaf(ev, sr.z, En[j4 * 4 + 2]);
        En[j4 * 4 + 3] = fmaf(ev, sr.w, En[j4 * 4 + 3]);
      }
    }
    #pragma unroll
    for (int j = 0; j < 32; ++j) E[j] = En[j];
    asm volatile("s_waitcnt lgkmcnt(0)" ::: "memory");
  }

  // new_q[lane] = sum_j E[lane][j] * q[m][j]
  const float* qr = q + (size_t)m * 32;
  float nq = 0.f;
  #pragma unroll
  for (int j4 = 0; j4 < 8; ++j4) {
    float4 qv = *reinterpret_cast<const float4*>(qr + j4 * 4);
    nq = fmaf(E[j4 * 4 + 0], qv.x, nq);
    nq = fmaf(E[j4 * 4 + 1], qv.y, nq);
    nq = fmaf(E[j4 * 4 + 2], qv.z, nq);
    nq = fmaf(E[j4 * 4 + 3], qv.w, nq);
  }
  out_q[(size_t)m * 32 + lane] = nq;
}

extern "C" void kernel_launch(void* const* d_in, const int* in_sizes, int n_in,
                              void* d_out, int out_size, void* d_ws, size_t ws_size,
                              hipStream_t stream) {
  const float* q    = (const float*)d_in[0];
  const float* p    = (const float*)d_in[1];
  const float* t    = (const float*)d_in[2];
  const float* dt   = (const float*)d_in[3];
  const float* W0   = (const float*)d_in[4];
  const float* b0   = (const float*)d_in[5];
  const float* W1   = (const float*)d_in[6];
  const float* b1   = (const float*)d_in[7];
  const float* W2   = (const float*)d_in[8];
  const float* b2   = (const float*)d_in[9];
  const float* W3   = (const float*)d_in[10];
  const float* b3   = (const float*)d_in[11];
  const float* Wout = (const float*)d_in[12];
  const float* bout = (const float*)d_in[13];

  float* ws   = (float*)d_ws;
  float* h1   = ws;                            // B*512
  float* h2   = ws + (size_t)BTOT * 512;       // B*512
  float* flat = ws + (size_t)2 * BTOT * 512;   // B*1024

  dim3 blk(256);
  dim3 gH(BTOT / 128, 512 / 128);
  dim3 gO(BTOT / 128, 1024 / 128);

  mlp_layer_kernel<true ><<<gH, blk, 0, stream>>>(p,  32,  32,  t, W0,   b0,   h1,   512);
  mlp_layer_kernel<true ><<<gH, blk, 0, stream>>>(h1, 512, 512, t, W1,   b1,   h2,   512);
  mlp_layer_kernel<true ><<<gH, blk, 0, stream>>>(h2, 512, 512, t, W2,   b2,   h1,   512);
  mlp_layer_kernel<true ><<<gH, blk, 0, stream>>>(h1, 512, 512, t, W3,   b3,   h2,   512);
  mlp_layer_kernel<false><<<gO, blk, 0, stream>>>(h2, 512, 512, t, Wout, bout, flat, 1024);

  float* out_q     = (float*)d_out;
  float* out_dlogp = out_q + (size_t)BTOT * 32;
  expm_kernel<<<BTOT / 8, blk, 0, stream>>>(flat, q, dt, out_q, out_dlogp);
}

// Round 3
// 697.123 us; speedup vs baseline: 3.3070x; 3.3070x over previous
//
#include <hip/hip_runtime.h>
#include <hip/hip_bf16.h>
#include <math.h>

#define BTOT 16384

__device__ __forceinline__ float selu_f(float x) {
  const float scale = 1.0507009873554805f;
  const float alpha = 1.6732632423543772f;
  return scale * (x > 0.0f ? x : alpha * expm1f(x));
}

// ---------------- MLP GEMM layers (unchanged this round) ----------------
// Y[b][n] = act( sum_{k<Kc} X[b][k]*W[k][n] + t[b]*W[Kc][n] + bias[n] )
template<bool DO_SELU>
__global__ __launch_bounds__(256) void mlp_layer_kernel(
    const float* __restrict__ X, int ldx, int Kc,
    const float* __restrict__ tvec,
    const float* __restrict__ W,     // [(Kc+1) x N]
    const float* __restrict__ bias,  // [N]
    float* __restrict__ Y, int N)
{
  __shared__ float sX[128][33];
  __shared__ float sW[32][128];
  const int tid = threadIdx.x;
  const int bm = blockIdx.x, bn = blockIdx.y;
  const int tx = tid & 15, ty = tid >> 4;
  const int rowbase = bm * 128, colbase = bn * 128;

  float acc[8][8];
  #pragma unroll
  for (int i = 0; i < 8; ++i)
    #pragma unroll
    for (int j = 0; j < 8; ++j) acc[i][j] = 0.0f;

  for (int k0 = 0; k0 < Kc; k0 += 32) {
    {
      const int r0 = tid >> 3;
      const int kc = (tid & 7) << 2;
      #pragma unroll
      for (int pp = 0; pp < 4; ++pp) {
        int r = r0 + pp * 32;
        float4 v = *reinterpret_cast<const float4*>(
            X + (size_t)(rowbase + r) * ldx + k0 + kc);
        sX[r][kc + 0] = v.x; sX[r][kc + 1] = v.y;
        sX[r][kc + 2] = v.z; sX[r][kc + 3] = v.w;
      }
    }
    {
      const int kk0 = tid >> 5;
      const int cc = (tid & 31) << 2;
      #pragma unroll
      for (int pp = 0; pp < 4; ++pp) {
        int kk = kk0 + pp * 8;
        *reinterpret_cast<float4*>(&sW[kk][cc]) =
            *reinterpret_cast<const float4*>(W + (size_t)(k0 + kk) * N + colbase + cc);
      }
    }
    __syncthreads();
    #pragma unroll
    for (int kk = 0; kk < 32; ++kk) {
      float a[8], b[8];
      #pragma unroll
      for (int i = 0; i < 8; ++i) a[i] = sX[ty * 8 + i][kk];
      float4 bv0 = *reinterpret_cast<const float4*>(&sW[kk][tx * 8]);
      float4 bv1 = *reinterpret_cast<const float4*>(&sW[kk][tx * 8 + 4]);
      b[0] = bv0.x; b[1] = bv0.y; b[2] = bv0.z; b[3] = bv0.w;
      b[4] = bv1.x; b[5] = bv1.y; b[6] = bv1.z; b[7] = bv1.w;
      #pragma unroll
      for (int i = 0; i < 8; ++i)
        #pragma unroll
        for (int j = 0; j < 8; ++j) acc[i][j] = fmaf(a[i], b[j], acc[i][j]);
    }
    __syncthreads();
  }

  float4 wl0 = *reinterpret_cast<const float4*>(W + (size_t)Kc * N + colbase + tx * 8);
  float4 wl1 = *reinterpret_cast<const float4*>(W + (size_t)Kc * N + colbase + tx * 8 + 4);
  float4 bb0 = *reinterpret_cast<const float4*>(bias + colbase + tx * 8);
  float4 bb1 = *reinterpret_cast<const float4*>(bias + colbase + tx * 8 + 4);
  float wl[8] = {wl0.x, wl0.y, wl0.z, wl0.w, wl1.x, wl1.y, wl1.z, wl1.w};
  float bb[8] = {bb0.x, bb0.y, bb0.z, bb0.w, bb1.x, bb1.y, bb1.z, bb1.w};
  #pragma unroll
  for (int i = 0; i < 8; ++i) {
    int row = rowbase + ty * 8 + i;
    float tv = tvec[row];
    float o[8];
    #pragma unroll
    for (int j = 0; j < 8; ++j) {
      float v = acc[i][j] + tv * wl[j] + bb[j];
      o[j] = DO_SELU ? selu_f(v) : v;
    }
    float4* dst = reinterpret_cast<float4*>(Y + (size_t)row * N + colbase + tx * 8);
    dst[0] = make_float4(o[0], o[1], o[2], o[3]);
    dst[1] = make_float4(o[4], o[5], o[6], o[7]);
  }
}

// ---------------- expm: one 32x32 matrix per 64-lane wave ----------------
// lane = 2*r + h; lane owns elements [h*16, h*16+16) of row r.
// LDS layout (per wave, per buffer): element (i,c) at dword
//   i*32 + (c ^ ((i&3)<<2))   with c = h*16 + j4*4 + e
// -> read offsets fold to compile-time immediates (per-lane base = h*16),
//    staging writes spread across all 32 banks.
#define WAITLDS asm volatile("s_waitcnt lgkmcnt(0)" ::: "memory")

// Z = X_row * Y  (X: own half-row in regs; Y: matrix in LDS, swizzled layout)
__device__ __forceinline__ void mm16(const float (&X)[16], const float* __restrict__ Y,
                                     int h, float (&Z)[16]) {
  #pragma unroll
  for (int j = 0; j < 16; ++j) Z[j] = 0.0f;
  const float* Yh = Y + h * 16;  // per-lane column-half base (dwords)
  #pragma unroll
  for (int k2 = 0; k2 < 16; ++k2) {
    float mine  = X[k2];
    float other = __shfl_xor(mine, 1);
    float xlo = h ? other : mine;   // X_row[k2]
    float xhi = h ? mine  : other;  // X_row[16 + k2]
    #pragma unroll
    for (int j4 = 0; j4 < 4; ++j4) {
      const int off = (j4 * 4) ^ ((k2 & 3) << 2);   // compile-time
      float4 ylo = *reinterpret_cast<const float4*>(Yh + k2 * 32 + off);
      float4 yhi = *reinterpret_cast<const float4*>(Yh + (k2 + 16) * 32 + off);
      Z[j4 * 4 + 0] = fmaf(xlo, ylo.x, fmaf(xhi, yhi.x, Z[j4 * 4 + 0]));
      Z[j4 * 4 + 1] = fmaf(xlo, ylo.y, fmaf(xhi, yhi.y, Z[j4 * 4 + 1]));
      Z[j4 * 4 + 2] = fmaf(xlo, ylo.z, fmaf(xhi, yhi.z, Z[j4 * 4 + 2]));
      Z[j4 * 4 + 3] = fmaf(xlo, ylo.w, fmaf(xhi, yhi.w, Z[j4 * 4 + 3]));
    }
  }
}

__device__ __forceinline__ void stage(const float (&X)[16], float* __restrict__ Ybase,
                                      const int (&woff)[4]) {
  #pragma unroll
  for (int j4 = 0; j4 < 4; ++j4)
    *reinterpret_cast<float4*>(Ybase + woff[j4]) =
        make_float4(X[j4 * 4 + 0], X[j4 * 4 + 1], X[j4 * 4 + 2], X[j4 * 4 + 3]);
}

__global__ __launch_bounds__(256) void expm_kernel(
    const float* __restrict__ flat,   // [B,1024]
    const float* __restrict__ q,      // [B,32]
    const float* __restrict__ dtp,    // [1]
    float* __restrict__ out_q,        // [B,32]
    float* __restrict__ out_dlogp)    // [B]
{
  __shared__ float S[4][2][32][32];   // [wave][buf][row][swizzled col] = 32 KiB
  const int tid  = threadIdx.x;
  const int w    = tid >> 6;
  const int lane = tid & 63;
  const int r = lane >> 1, h = lane & 1;
  const int m = blockIdx.x * 4 + w;
  const float dt = dtp[0];

  float* SA = &S[w][0][0][0];
  float* SB = &S[w][1][0][0];

  int woff[4];
  #pragma unroll
  for (int j4 = 0; j4 < 4; ++j4)
    woff[j4] = r * 32 + h * 16 + ((j4 * 4) ^ ((r & 3) << 2));

  // load own half-row of dt*clip(dense): lane l reads bytes [l*64, l*64+64)
  float A[16];
  {
    const float* fr = flat + (size_t)m * 1024 + lane * 16;
    #pragma unroll
    for (int j4 = 0; j4 < 4; ++j4) {
      float4 v = *reinterpret_cast<const float4*>(fr + j4 * 4);
      A[j4 * 4 + 0] = dt * fminf(fmaxf(v.x, -20.f), 20.f);
      A[j4 * 4 + 1] = dt * fminf(fmaxf(v.y, -20.f), 20.f);
      A[j4 * 4 + 2] = dt * fminf(fmaxf(v.z, -20.f), 20.f);
      A[j4 * 4 + 3] = dt * fminf(fmaxf(v.w, -20.f), 20.f);
    }
  }

  // dlogp = trace(A) (pre-scaling); static-index select of own diag element
  float tr = 0.0f;
  #pragma unroll
  for (int j = 0; j < 16; ++j) tr += ((h * 16 + j) == r) ? A[j] : 0.0f;
  #pragma unroll
  for (int off = 1; off < 64; off <<= 1) tr += __shfl_xor(tr, off);
  if (lane == 0) out_dlogp[m] = tr;

  // stage unscaled A, compute 1-norm (max column abs-sum)
  stage(A, SA, woff);
  WAITLDS;
  float cs = 0.0f;
  {
    const int c = lane & 31;
    #pragma unroll
    for (int i = 0; i < 32; ++i)
      cs += fabsf(SA[i * 32 + (c ^ ((i & 3) << 2))]);
  }
  float nrm = cs;
  #pragma unroll
  for (int off = 1; off < 32; off <<= 1) nrm = fmaxf(nrm, __shfl_xor(nrm, off));

  int s = 0;
  if (nrm > 1.0f) {
    s = (int)ceilf(log2f(nrm));
    s = s < 0 ? 0 : (s > 12 ? 12 : s);
  }
  const float sc = exp2f(-(float)s);
  #pragma unroll
  for (int j = 0; j < 16; ++j) A[j] *= sc;
  stage(A, SA, woff);
  WAITLDS;

  // Paterson–Stockmeyer order-8 Taylor: 4 matmuls
  float A2[16]; mm16(A,  SA, h, A2);
  float A3[16]; mm16(A2, SA, h, A3);
  stage(A3, SB, woff);
  WAITLDS;

  float Wk[16], Z[16];
  #pragma unroll
  for (int j = 0; j < 16; ++j) {            // C2 = I/720 + A/5040 + A2/40320
    float dI = ((h * 16 + j) == r) ? 1.0f : 0.0f;
    Wk[j] = (1.0f/720.0f) * dI + (1.0f/5040.0f) * A[j] + (1.0f/40320.0f) * A2[j];
  }
  mm16(Wk, SB, h, Z);                        // Z = C2*A3
  #pragma unroll
  for (int j = 0; j < 16; ++j) {            // W = C1 + C2*A3
    float dI = ((h * 16 + j) == r) ? 1.0f : 0.0f;
    Wk[j] = Z[j] + (1.0f/6.0f) * dI + (1.0f/24.0f) * A[j] + (1.0f/120.0f) * A2[j];
  }
  mm16(Wk, SB, h, Z);                        // Z = (C1 + C2*A3)*A3
  float E[16];
  #pragma unroll
  for (int j = 0; j < 16; ++j) {            // E = C0 + Z = I + A + A2/2 + Z
    float dI = ((h * 16 + j) == r) ? 1.0f : 0.0f;
    E[j] = Z[j] + dI + A[j] + 0.5f * A2[j];
  }

  // squaring: E = E^(2^s); s is wave-uniform
  #pragma unroll 1
  for (int it = 0; it < s; ++it) {
    stage(E, SB, woff);
    WAITLDS;
    float En[16];
    mm16(E, SB, h, En);
    #pragma unroll
    for (int j = 0; j < 16; ++j) E[j] = En[j];
  }

  // new_q[r] = sum_j E[r][j]*q[j]  (half-sums combined via shfl)
  const float* qr = q + (size_t)m * 32 + h * 16;
  float nq = 0.0f;
  #pragma unroll
  for (int j4 = 0; j4 < 4; ++j4) {
    float4 qv = *reinterpret_cast<const float4*>(qr + j4 * 4);
    nq = fmaf(E[j4 * 4 + 0], qv.x, nq);
    nq = fmaf(E[j4 * 4 + 1], qv.y, nq);
    nq = fmaf(E[j4 * 4 + 2], qv.z, nq);
    nq = fmaf(E[j4 * 4 + 3], qv.w, nq);
  }
  nq += __shfl_xor(nq, 1);
  if (h == 0) out_q[(size_t)m * 32 + r] = nq;
}

extern "C" void kernel_launch(void* const* d_in, const int* in_sizes, int n_in,
                              void* d_out, int out_size, void* d_ws, size_t ws_size,
                              hipStream_t stream) {
  const float* q    = (const float*)d_in[0];
  const float* p    = (const float*)d_in[1];
  const float* t    = (const float*)d_in[2];
  const float* dt   = (const float*)d_in[3];
  const float* W0   = (const float*)d_in[4];
  const float* b0   = (const float*)d_in[5];
  const float* W1   = (const float*)d_in[6];
  const float* b1   = (const float*)d_in[7];
  const float* W2   = (const float*)d_in[8];
  const float* b2   = (const float*)d_in[9];
  const float* W3   = (const float*)d_in[10];
  const float* b3   = (const float*)d_in[11];
  const float* Wout = (const float*)d_in[12];
  const float* bout = (const float*)d_in[13];

  float* ws   = (float*)d_ws;
  float* h1   = ws;                            // B*512
  float* h2   = ws + (size_t)BTOT * 512;       // B*512
  float* flat = ws + (size_t)2 * BTOT * 512;   // B*1024

  dim3 blk(256);
  dim3 gH(BTOT / 128, 512 / 128);
  dim3 gO(BTOT / 128, 1024 / 128);

  mlp_layer_kernel<true ><<<gH, blk, 0, stream>>>(p,  32,  32,  t, W0,   b0,   h1,   512);
  mlp_layer_kernel<true ><<<gH, blk, 0, stream>>>(h1, 512, 512, t, W1,   b1,   h2,   512);
  mlp_layer_kernel<true ><<<gH, blk, 0, stream>>>(h2, 512, 512, t, W2,   b2,   h1,   512);
  mlp_layer_kernel<true ><<<gH, blk, 0, stream>>>(h1, 512, 512, t, W3,   b3,   h2,   512);
  mlp_layer_kernel<false><<<gO, blk, 0, stream>>>(h2, 512, 512, t, Wout, bout, flat, 1024);

  float* out_q     = (float*)d_out;
  float* out_dlogp = out_q + (size_t)BTOT * 32;
  expm_kernel<<<BTOT / 4, blk, 0, stream>>>(flat, q, dt, out_q, out_dlogp);
}

// Round 4
// 265.381 us; speedup vs baseline: 8.6871x; 2.6269x over previous
//
#include <hip/hip_runtime.h>
#include <hip/hip_bf16.h>
#include <math.h>

#define BTOT 16384

typedef __attribute__((ext_vector_type(8))) short short8;
typedef __attribute__((ext_vector_type(4))) float f32x4;

__device__ __forceinline__ float selu_f(float x) {
  const float scale = 1.0507009873554805f;
  const float alpha = 1.6732632423543772f;
  return scale * (x > 0.0f ? x : alpha * expm1f(x));
}

// ---------------- prep: p -> bf16 ----------------
__global__ __launch_bounds__(256) void convert_p_kernel(
    const float* __restrict__ p, __hip_bfloat16* __restrict__ out) {
  int i = (blockIdx.x * 256 + threadIdx.x) * 4;
  float4 v = *reinterpret_cast<const float4*>(p + i);
  out[i + 0] = __float2bfloat16(v.x);
  out[i + 1] = __float2bfloat16(v.y);
  out[i + 2] = __float2bfloat16(v.z);
  out[i + 3] = __float2bfloat16(v.w);
}

// ---------------- prep: W[K][N] f32 -> Wt[N][K] bf16 (t-row excluded) ---------
__global__ __launch_bounds__(256) void transpose_w_kernel(
    const float* __restrict__ W, __hip_bfloat16* __restrict__ Wt, int K, int N) {
  __shared__ float tile[32][33];
  const int kb = blockIdx.x * 32, nb = blockIdx.y * 32;
  const int tx = threadIdx.x & 31, ty = threadIdx.x >> 5;  // ty: 0..7
  #pragma unroll
  for (int rr = 0; rr < 4; ++rr) {
    int kl = ty + rr * 8;
    tile[kl][tx] = W[(size_t)(kb + kl) * N + nb + tx];
  }
  __syncthreads();
  #pragma unroll
  for (int rr = 0; rr < 4; ++rr) {
    int nl = ty + rr * 8;
    Wt[(size_t)(nb + nl) * K + kb + tx] = __float2bfloat16(tile[tx][nl]);
  }
}

// ---------------- MFMA MLP layer ----------------
// Y[row][col] = act( sum_k X[row][k]*Wt[col][k] + t[row]*Wlast[col] + bias[col] )
// 128x128 tile, BK in {32,64}; 4 waves, each 64x64 out (4x4 frags 16x16x32).
// Staging: global_load_lds 16B, linear LDS dest, XOR-pre-swizzled global source;
// ds_read uses the same XOR -> consistent involution (rule #21), 2-way-free banks.
// Fragment k-mapping: elem e of group g = k 8g+e for BOTH A and B: any internal
// HW k-order gives the same dot product as long as A/B use the same bijection.
template<int BK, bool DO_SELU, bool OUT_F32>
__global__ __launch_bounds__(256) void mlp_mfma_kernel(
    const __hip_bfloat16* __restrict__ X, int ldx, int Kc,
    const float* __restrict__ tvec,
    const __hip_bfloat16* __restrict__ Wt,    // [N][Kc] bf16
    const float* __restrict__ Wlast,          // t-row, fp32 [N]
    const float* __restrict__ bias,           // fp32 [N]
    void* __restrict__ Yout, int ldy) {
  constexpr int NBLK = BK / 8;          // 16B blocks per row
  constexpr int AB = 128 * BK * 2;      // bytes per tile
  constexpr int IPW = AB / 1024 / 4;    // load_lds instrs per wave per tile
  __shared__ char lds[4 * AB];          // [buf][A|B]
  const int tid = threadIdx.x;
  const int w = tid >> 6, lane = tid & 63;
  const int wr = w >> 1, wc = w & 1;
  const int rowbase = blockIdx.x * 128, colbase = blockIdx.y * 128;

  // staging source addresses (pre-swizzled kb so linear LDS dest = swizzled data)
  const __hip_bfloat16* srcA[IPW];
  const __hip_bfloat16* srcB[IPW];
  int ldsoff[IPW];
  #pragma unroll
  for (int i = 0; i < IPW; ++i) {
    int f = (w * IPW + i) * 64 + lane;
    int r = f / NBLK, slot = f % NBLK;
    int kb = slot ^ (r & (NBLK - 1));
    srcA[i] = X + (size_t)(rowbase + r) * ldx + kb * 8;
    srcB[i] = Wt + (size_t)(colbase + r) * Kc + kb * 8;
    ldsoff[i] = (w * IPW + i) * 1024;
  }

  f32x4 acc[4][4] = {};

  int aoff[4], amask[4], boff[4], bmask[4];
  #pragma unroll
  for (int i = 0; i < 4; ++i) {
    int ra = wr * 64 + i * 16 + (lane & 15);
    aoff[i] = ra * BK * 2;
    amask[i] = ra & (NBLK - 1);
    int cb = wc * 64 + i * 16 + (lane & 15);
    boff[i] = cb * BK * 2;
    bmask[i] = cb & (NBLK - 1);
  }
  const int kgrp = lane >> 4;

  auto stage_tile = [&](int buf, int t) {
    char* ab = lds + buf * 2 * AB;
    #pragma unroll
    for (int i = 0; i < IPW; ++i) {
      __builtin_amdgcn_global_load_lds(
          (const __attribute__((address_space(1))) void*)(srcA[i] + t * BK),
          (__attribute__((address_space(3))) void*)(ab + ldsoff[i]), 16, 0, 0);
      __builtin_amdgcn_global_load_lds(
          (const __attribute__((address_space(1))) void*)(srcB[i] + t * BK),
          (__attribute__((address_space(3))) void*)(ab + AB + ldsoff[i]), 16, 0, 0);
    }
  };

  auto compute_tile = [&](int buf) {
    const char* Abse = lds + buf * 2 * AB;
    const char* Bbse = Abse + AB;
    #pragma unroll
    for (int kh = 0; kh < BK / 32; ++kh) {
      short8 a[4], b[4];
      const int kb = kh * 4 + kgrp;
      #pragma unroll
      for (int i = 0; i < 4; ++i) {
        a[i] = *reinterpret_cast<const short8*>(Abse + aoff[i] + ((kb ^ amask[i]) * 16));
        b[i] = *reinterpret_cast<const short8*>(Bbse + boff[i] + ((kb ^ bmask[i]) * 16));
      }
      #pragma unroll
      for (int i = 0; i < 4; ++i)
        #pragma unroll
        for (int j = 0; j < 4; ++j)
          acc[i][j] = __builtin_amdgcn_mfma_f32_16x16x32_bf16(a[i], b[j], acc[i][j], 0, 0, 0);
    }
  };

  const int nt = Kc / BK;
  stage_tile(0, 0);
  asm volatile("s_waitcnt vmcnt(0)" ::: "memory");
  __syncthreads();
  int buf = 0;
  #pragma unroll 1
  for (int t = 0; t < nt - 1; ++t) {
    stage_tile(buf ^ 1, t + 1);
    compute_tile(buf);
    asm volatile("s_waitcnt vmcnt(0)" ::: "memory");
    __syncthreads();
    buf ^= 1;
  }
  compute_tile(buf);

  // epilogue: D layout col=lane&15, row=(lane>>4)*4+e [measured m89/m91]
  const int colloc = lane & 15;
  const int rowgrp = lane >> 4;
  float wl[4], bb[4];
  #pragma unroll
  for (int j = 0; j < 4; ++j) {
    int col = colbase + wc * 64 + j * 16 + colloc;
    wl[j] = Wlast[col];
    bb[j] = bias[col];
  }
  #pragma unroll
  for (int i = 0; i < 4; ++i) {
    #pragma unroll
    for (int e = 0; e < 4; ++e) {
      int row = rowbase + wr * 64 + i * 16 + rowgrp * 4 + e;
      float tv = tvec[row];
      #pragma unroll
      for (int j = 0; j < 4; ++j) {
        float v = acc[i][j][e] + tv * wl[j] + bb[j];
        if (DO_SELU) v = selu_f(v);
        int col = colbase + wc * 64 + j * 16 + colloc;
        if (OUT_F32)
          reinterpret_cast<float*>(Yout)[(size_t)row * ldy + col] = v;
        else
          reinterpret_cast<__hip_bfloat16*>(Yout)[(size_t)row * ldy + col] = __float2bfloat16(v);
      }
    }
  }
}

// ---------------- expm: one 32x32 matrix per 64-lane wave (round-3, passing) ---
#define WAITLDS asm volatile("s_waitcnt lgkmcnt(0)" ::: "memory")

__device__ __forceinline__ void mm16(const float (&X)[16], const float* __restrict__ Y,
                                     int h, float (&Z)[16]) {
  #pragma unroll
  for (int j = 0; j < 16; ++j) Z[j] = 0.0f;
  const float* Yh = Y + h * 16;
  #pragma unroll
  for (int k2 = 0; k2 < 16; ++k2) {
    float mine = X[k2];
    float other = __shfl_xor(mine, 1);
    float xlo = h ? other : mine;
    float xhi = h ? mine : other;
    #pragma unroll
    for (int j4 = 0; j4 < 4; ++j4) {
      const int off = (j4 * 4) ^ ((k2 & 3) << 2);
      float4 ylo = *reinterpret_cast<const float4*>(Yh + k2 * 32 + off);
      float4 yhi = *reinterpret_cast<const float4*>(Yh + (k2 + 16) * 32 + off);
      Z[j4 * 4 + 0] = fmaf(xlo, ylo.x, fmaf(xhi, yhi.x, Z[j4 * 4 + 0]));
      Z[j4 * 4 + 1] = fmaf(xlo, ylo.y, fmaf(xhi, yhi.y, Z[j4 * 4 + 1]));
      Z[j4 * 4 + 2] = fmaf(xlo, ylo.z, fmaf(xhi, yhi.z, Z[j4 * 4 + 2]));
      Z[j4 * 4 + 3] = fmaf(xlo, ylo.w, fmaf(xhi, yhi.w, Z[j4 * 4 + 3]));
    }
  }
}

__device__ __forceinline__ void stage_m(const float (&X)[16], float* __restrict__ Ybase,
                                        const int (&woff)[4]) {
  #pragma unroll
  for (int j4 = 0; j4 < 4; ++j4)
    *reinterpret_cast<float4*>(Ybase + woff[j4]) =
        make_float4(X[j4 * 4 + 0], X[j4 * 4 + 1], X[j4 * 4 + 2], X[j4 * 4 + 3]);
}

__global__ __launch_bounds__(256) void expm_kernel(
    const float* __restrict__ flat, const float* __restrict__ q,
    const float* __restrict__ dtp, float* __restrict__ out_q,
    float* __restrict__ out_dlogp) {
  __shared__ float S[4][2][32][32];
  const int tid = threadIdx.x;
  const int w = tid >> 6;
  const int lane = tid & 63;
  const int r = lane >> 1, h = lane & 1;
  const int m = blockIdx.x * 4 + w;
  const float dt = dtp[0];

  float* SA = &S[w][0][0][0];
  float* SB = &S[w][1][0][0];

  int woff[4];
  #pragma unroll
  for (int j4 = 0; j4 < 4; ++j4)
    woff[j4] = r * 32 + h * 16 + ((j4 * 4) ^ ((r & 3) << 2));

  float A[16];
  {
    const float* fr = flat + (size_t)m * 1024 + lane * 16;
    #pragma unroll
    for (int j4 = 0; j4 < 4; ++j4) {
      float4 v = *reinterpret_cast<const float4*>(fr + j4 * 4);
      A[j4 * 4 + 0] = dt * fminf(fmaxf(v.x, -20.f), 20.f);
      A[j4 * 4 + 1] = dt * fminf(fmaxf(v.y, -20.f), 20.f);
      A[j4 * 4 + 2] = dt * fminf(fmaxf(v.z, -20.f), 20.f);
      A[j4 * 4 + 3] = dt * fminf(fmaxf(v.w, -20.f), 20.f);
    }
  }

  float tr = 0.0f;
  #pragma unroll
  for (int j = 0; j < 16; ++j) tr += ((h * 16 + j) == r) ? A[j] : 0.0f;
  #pragma unroll
  for (int off = 1; off < 64; off <<= 1) tr += __shfl_xor(tr, off);
  if (lane == 0) out_dlogp[m] = tr;

  stage_m(A, SA, woff);
  WAITLDS;
  float cs = 0.0f;
  {
    const int c = lane & 31;
    #pragma unroll
    for (int i = 0; i < 32; ++i)
      cs += fabsf(SA[i * 32 + (c ^ ((i & 3) << 2))]);
  }
  float nrm = cs;
  #pragma unroll
  for (int off = 1; off < 32; off <<= 1) nrm = fmaxf(nrm, __shfl_xor(nrm, off));

  int s = 0;
  if (nrm > 1.0f) {
    s = (int)ceilf(log2f(nrm));
    s = s < 0 ? 0 : (s > 12 ? 12 : s);
  }
  const float sc = exp2f(-(float)s);
  #pragma unroll
  for (int j = 0; j < 16; ++j) A[j] *= sc;
  stage_m(A, SA, woff);
  WAITLDS;

  float A2[16]; mm16(A, SA, h, A2);
  float A3[16]; mm16(A2, SA, h, A3);
  stage_m(A3, SB, woff);
  WAITLDS;

  float Wk[16], Z[16];
  #pragma unroll
  for (int j = 0; j < 16; ++j) {
    float dI = ((h * 16 + j) == r) ? 1.0f : 0.0f;
    Wk[j] = (1.0f/720.0f) * dI + (1.0f/5040.0f) * A[j] + (1.0f/40320.0f) * A2[j];
  }
  mm16(Wk, SB, h, Z);
  #pragma unroll
  for (int j = 0; j < 16; ++j) {
    float dI = ((h * 16 + j) == r) ? 1.0f : 0.0f;
    Wk[j] = Z[j] + (1.0f/6.0f) * dI + (1.0f/24.0f) * A[j] + (1.0f/120.0f) * A2[j];
  }
  mm16(Wk, SB, h, Z);
  float E[16];
  #pragma unroll
  for (int j = 0; j < 16; ++j) {
    float dI = ((h * 16 + j) == r) ? 1.0f : 0.0f;
    E[j] = Z[j] + dI + A[j] + 0.5f * A2[j];
  }

  #pragma unroll 1
  for (int it = 0; it < s; ++it) {
    stage_m(E, SB, woff);
    WAITLDS;
    float En[16];
    mm16(E, SB, h, En);
    #pragma unroll
    for (int j = 0; j < 16; ++j) E[j] = En[j];
  }

  const float* qr = q + (size_t)m * 32 + h * 16;
  float nq = 0.0f;
  #pragma unroll
  for (int j4 = 0; j4 < 4; ++j4) {
    float4 qv = *reinterpret_cast<const float4*>(qr + j4 * 4);
    nq = fmaf(E[j4 * 4 + 0], qv.x, nq);
    nq = fmaf(E[j4 * 4 + 1], qv.y, nq);
    nq = fmaf(E[j4 * 4 + 2], qv.z, nq);
    nq = fmaf(E[j4 * 4 + 3], qv.w, nq);
  }
  nq += __shfl_xor(nq, 1);
  if (h == 0) out_q[(size_t)m * 32 + r] = nq;
}

extern "C" void kernel_launch(void* const* d_in, const int* in_sizes, int n_in,
                              void* d_out, int out_size, void* d_ws, size_t ws_size,
                              hipStream_t stream) {
  const float* q    = (const float*)d_in[0];
  const float* p    = (const float*)d_in[1];
  const float* t    = (const float*)d_in[2];
  const float* dt   = (const float*)d_in[3];
  const float* W0   = (const float*)d_in[4];
  const float* b0   = (const float*)d_in[5];
  const float* W1   = (const float*)d_in[6];
  const float* b1   = (const float*)d_in[7];
  const float* W2   = (const float*)d_in[8];
  const float* b2   = (const float*)d_in[9];
  const float* W3   = (const float*)d_in[10];
  const float* b3   = (const float*)d_in[11];
  const float* Wout = (const float*)d_in[12];
  const float* bout = (const float*)d_in[13];

  // ws layout
  float* flat = (float*)d_ws;                                   // B*1024 f32
  __hip_bfloat16* act1 = (__hip_bfloat16*)((char*)d_ws + (size_t)BTOT * 1024 * 4);
  __hip_bfloat16* act2 = act1 + (size_t)BTOT * 512;
  __hip_bfloat16* pbf  = act2 + (size_t)BTOT * 512;
  __hip_bfloat16* Wt0  = pbf + (size_t)BTOT * 32;
  __hip_bfloat16* Wt1  = Wt0 + 512 * 32;
  __hip_bfloat16* Wt2  = Wt1 + 512 * 512;
  __hip_bfloat16* Wt3  = Wt2 + 512 * 512;
  __hip_bfloat16* WtO  = Wt3 + 512 * 512;

  dim3 blk(256);
  convert_p_kernel<<<BTOT * 32 / 1024, blk, 0, stream>>>(p, pbf);
  transpose_w_kernel<<<dim3(1, 16),  blk, 0, stream>>>(W0,   Wt0, 32,  512);
  transpose_w_kernel<<<dim3(16, 16), blk, 0, stream>>>(W1,   Wt1, 512, 512);
  transpose_w_kernel<<<dim3(16, 16), blk, 0, stream>>>(W2,   Wt2, 512, 512);
  transpose_w_kernel<<<dim3(16, 16), blk, 0, stream>>>(W3,   Wt3, 512, 512);
  transpose_w_kernel<<<dim3(16, 32), blk, 0, stream>>>(Wout, WtO, 512, 1024);

  mlp_mfma_kernel<32, true, false><<<dim3(128, 4), blk, 0, stream>>>(
      pbf, 32, 32, t, Wt0, W0 + 32 * 512, b0, act1, 512);
  mlp_mfma_kernel<64, true, false><<<dim3(128, 4), blk, 0, stream>>>(
      act1, 512, 512, t, Wt1, W1 + 512 * 512, b1, act2, 512);
  mlp_mfma_kernel<64, true, false><<<dim3(128, 4), blk, 0, stream>>>(
      act2, 512, 512, t, Wt2, W2 + 512 * 512, b2, act1, 512);
  mlp_mfma_kernel<64, true, false><<<dim3(128, 4), blk, 0, stream>>>(
      act1, 512, 512, t, Wt3, W3 + 512 * 512, b3, act2, 512);
  mlp_mfma_kernel<64, false, true><<<dim3(128, 8), blk, 0, stream>>>(
      act2, 512, 512, t, WtO, Wout + 512 * 1024, bout, flat, 1024);

  float* out_q     = (float*)d_out;
  float* out_dlogp = out_q + (size_t)BTOT * 32;
  expm_kernel<<<BTOT / 4, blk, 0, stream>>>(flat, q, dt, out_q, out_dlogp);
}

// Round 5
// 165.934 us; speedup vs baseline: 13.8934x; 1.5993x over previous
//
#include <hip/hip_runtime.h>
#include <hip/hip_bf16.h>
#include <math.h>

#define BTOT 16384

typedef __attribute__((ext_vector_type(8))) short short8;
typedef __attribute__((ext_vector_type(4))) float f32x4;
typedef __attribute__((ext_vector_type(16))) float f32x16;

__device__ __forceinline__ float selu_f(float x) {
  const float scale = 1.0507009873554805f;
  const float alpha = 1.6732632423543772f;
  return scale * (x > 0.0f ? x : alpha * expm1f(x));
}

// ---------------- prep: p -> bf16 ----------------
__global__ __launch_bounds__(256) void convert_p_kernel(
    const float* __restrict__ p, __hip_bfloat16* __restrict__ out) {
  int i = (blockIdx.x * 256 + threadIdx.x) * 4;
  float4 v = *reinterpret_cast<const float4*>(p + i);
  out[i + 0] = __float2bfloat16(v.x);
  out[i + 1] = __float2bfloat16(v.y);
  out[i + 2] = __float2bfloat16(v.z);
  out[i + 3] = __float2bfloat16(v.w);
}

// ---------------- prep: W[K][N] f32 -> Wt[N][K] bf16 (t-row excluded) ---------
__global__ __launch_bounds__(256) void transpose_w_kernel(
    const float* __restrict__ W, __hip_bfloat16* __restrict__ Wt, int K, int N) {
  __shared__ float tile[32][33];
  const int kb = blockIdx.x * 32, nb = blockIdx.y * 32;
  const int tx = threadIdx.x & 31, ty = threadIdx.x >> 5;  // ty: 0..7
  #pragma unroll
  for (int rr = 0; rr < 4; ++rr) {
    int kl = ty + rr * 8;
    tile[kl][tx] = W[(size_t)(kb + kl) * N + nb + tx];
  }
  __syncthreads();
  #pragma unroll
  for (int rr = 0; rr < 4; ++rr) {
    int nl = ty + rr * 8;
    Wt[(size_t)(nb + nl) * K + kb + tx] = __float2bfloat16(tile[tx][nl]);
  }
}

// ---------------- MFMA MLP layer (round-4, passing) ----------------
template<int BK, bool DO_SELU, bool OUT_F32>
__global__ __launch_bounds__(256) void mlp_mfma_kernel(
    const __hip_bfloat16* __restrict__ X, int ldx, int Kc,
    const float* __restrict__ tvec,
    const __hip_bfloat16* __restrict__ Wt,    // [N][Kc] bf16
    const float* __restrict__ Wlast,          // t-row, fp32 [N]
    const float* __restrict__ bias,           // fp32 [N]
    void* __restrict__ Yout, int ldy) {
  constexpr int NBLK = BK / 8;
  constexpr int AB = 128 * BK * 2;
  constexpr int IPW = AB / 1024 / 4;
  __shared__ char lds[4 * AB];
  const int tid = threadIdx.x;
  const int w = tid >> 6, lane = tid & 63;
  const int wr = w >> 1, wc = w & 1;
  const int rowbase = blockIdx.x * 128, colbase = blockIdx.y * 128;

  const __hip_bfloat16* srcA[IPW];
  const __hip_bfloat16* srcB[IPW];
  int ldsoff[IPW];
  #pragma unroll
  for (int i = 0; i < IPW; ++i) {
    int f = (w * IPW + i) * 64 + lane;
    int r = f / NBLK, slot = f % NBLK;
    int kb = slot ^ (r & (NBLK - 1));
    srcA[i] = X + (size_t)(rowbase + r) * ldx + kb * 8;
    srcB[i] = Wt + (size_t)(colbase + r) * Kc + kb * 8;
    ldsoff[i] = (w * IPW + i) * 1024;
  }

  f32x4 acc[4][4] = {};

  int aoff[4], amask[4], boff[4], bmask[4];
  #pragma unroll
  for (int i = 0; i < 4; ++i) {
    int ra = wr * 64 + i * 16 + (lane & 15);
    aoff[i] = ra * BK * 2;
    amask[i] = ra & (NBLK - 1);
    int cb = wc * 64 + i * 16 + (lane & 15);
    boff[i] = cb * BK * 2;
    bmask[i] = cb & (NBLK - 1);
  }
  const int kgrp = lane >> 4;

  auto stage_tile = [&](int buf, int t) {
    char* ab = lds + buf * 2 * AB;
    #pragma unroll
    for (int i = 0; i < IPW; ++i) {
      __builtin_amdgcn_global_load_lds(
          (const __attribute__((address_space(1))) void*)(srcA[i] + t * BK),
          (__attribute__((address_space(3))) void*)(ab + ldsoff[i]), 16, 0, 0);
      __builtin_amdgcn_global_load_lds(
          (const __attribute__((address_space(1))) void*)(srcB[i] + t * BK),
          (__attribute__((address_space(3))) void*)(ab + AB + ldsoff[i]), 16, 0, 0);
    }
  };

  auto compute_tile = [&](int buf) {
    const char* Abse = lds + buf * 2 * AB;
    const char* Bbse = Abse + AB;
    #pragma unroll
    for (int kh = 0; kh < BK / 32; ++kh) {
      short8 a[4], b[4];
      const int kb = kh * 4 + kgrp;
      #pragma unroll
      for (int i = 0; i < 4; ++i) {
        a[i] = *reinterpret_cast<const short8*>(Abse + aoff[i] + ((kb ^ amask[i]) * 16));
        b[i] = *reinterpret_cast<const short8*>(Bbse + boff[i] + ((kb ^ bmask[i]) * 16));
      }
      #pragma unroll
      for (int i = 0; i < 4; ++i)
        #pragma unroll
        for (int j = 0; j < 4; ++j)
          acc[i][j] = __builtin_amdgcn_mfma_f32_16x16x32_bf16(a[i], b[j], acc[i][j], 0, 0, 0);
    }
  };

  const int nt = Kc / BK;
  stage_tile(0, 0);
  asm volatile("s_waitcnt vmcnt(0)" ::: "memory");
  __syncthreads();
  int buf = 0;
  #pragma unroll 1
  for (int t = 0; t < nt - 1; ++t) {
    stage_tile(buf ^ 1, t + 1);
    compute_tile(buf);
    asm volatile("s_waitcnt vmcnt(0)" ::: "memory");
    __syncthreads();
    buf ^= 1;
  }
  compute_tile(buf);

  const int colloc = lane & 15;
  const int rowgrp = lane >> 4;
  float wl[4], bb[4];
  #pragma unroll
  for (int j = 0; j < 4; ++j) {
    int col = colbase + wc * 64 + j * 16 + colloc;
    wl[j] = Wlast[col];
    bb[j] = bias[col];
  }
  #pragma unroll
  for (int i = 0; i < 4; ++i) {
    #pragma unroll
    for (int e = 0; e < 4; ++e) {
      int row = rowbase + wr * 64 + i * 16 + rowgrp * 4 + e;
      float tv = tvec[row];
      #pragma unroll
      for (int j = 0; j < 4; ++j) {
        float v = acc[i][j][e] + tv * wl[j] + bb[j];
        if (DO_SELU) v = selu_f(v);
        int col = colbase + wc * 64 + j * 16 + colloc;
        if (OUT_F32)
          reinterpret_cast<float*>(Yout)[(size_t)row * ldy + col] = v;
        else
          reinterpret_cast<__hip_bfloat16*>(Yout)[(size_t)row * ldy + col] = __float2bfloat16(v);
      }
    }
  }
}

// ---------------- expm via split-bf16 MFMA ----------------
// One 32x32 matrix per 64-lane wave. All fp32 state in D-layout registers:
// lane (C=lane&31, G=lane>>5) holds elems (rd(reg), C), rd = (reg&3)+8*(reg>>2)+4G.
// LDS: matrices stored TRANSPOSED, packed u32 = (hi16(bf16)<<16 | lo16(bf16 of
// residual)), index T[i][j] @ i*32 + (j ^ ((i&7)<<2)). Product X*Y:
//   A-frag (X rows)   : 16x b32 column reads (conflict-free),
//   B-frag (Y cols)   : 4x b128 row reads,
//   D-write (stage)   : 4x b128 row writes.
// A/B use the same (G,e)->k bijection => correct for any HW internal k-order.
#define WAITLDS asm volatile("s_waitcnt lgkmcnt(0)" ::: "memory")

__device__ __forceinline__ unsigned int packhl(float x) {
  unsigned int xb = __float_as_uint(x);
  unsigned int hb = xb & 0xFFFF0000u;
  float lof = x - __uint_as_float(hb);
  return hb | (__float_as_uint(lof) >> 16);
}

__device__ __forceinline__ void stage_hl(const float (&X)[16],
                                         unsigned int* __restrict__ T,
                                         int C, int G) {
  #pragma unroll
  for (int gr = 0; gr < 4; ++gr) {
    uint4 v;
    v.x = packhl(X[gr * 4 + 0]);
    v.y = packhl(X[gr * 4 + 1]);
    v.z = packhl(X[gr * 4 + 2]);
    v.w = packhl(X[gr * 4 + 3]);
    int rd0 = gr * 8 + 4 * G;                       // 4-aligned
    *reinterpret_cast<uint4*>(T + C * 32 + (rd0 ^ ((C & 7) << 2))) = v;
  }
}

__device__ __forceinline__ f32x16 prod32(const unsigned int* __restrict__ TX,
                                         const unsigned int* __restrict__ TY,
                                         int C, int G, f32x16 acc) {
  #pragma unroll
  for (int h = 0; h < 2; ++h) {
    const int k0 = 16 * h + 8 * G;
    unsigned int au[8];
    #pragma unroll
    for (int e = 0; e < 8; ++e)
      au[e] = TX[(k0 + e) * 32 + (C ^ (e << 2))];   // (k&7)==e
    uint4 v0 = *reinterpret_cast<const uint4*>(TY + C * 32 + (k0 ^ ((C & 7) << 2)));
    uint4 v1 = *reinterpret_cast<const uint4*>(TY + C * 32 + ((k0 + 4) ^ ((C & 7) << 2)));
    unsigned int bu[8] = {v0.x, v0.y, v0.z, v0.w, v1.x, v1.y, v1.z, v1.w};
    union { short8 s; unsigned int u[4]; } ah, al, bh, bl;
    #pragma unroll
    for (int i = 0; i < 4; ++i) {
      ah.u[i] = __builtin_amdgcn_perm(au[2 * i + 1], au[2 * i], 0x07060302u);
      al.u[i] = __builtin_amdgcn_perm(au[2 * i + 1], au[2 * i], 0x05040100u);
      bh.u[i] = __builtin_amdgcn_perm(bu[2 * i + 1], bu[2 * i], 0x07060302u);
      bl.u[i] = __builtin_amdgcn_perm(bu[2 * i + 1], bu[2 * i], 0x05040100u);
    }
    acc = __builtin_amdgcn_mfma_f32_32x32x16_bf16(ah.s, bh.s, acc, 0, 0, 0);
    acc = __builtin_amdgcn_mfma_f32_32x32x16_bf16(ah.s, bl.s, acc, 0, 0, 0);
    acc = __builtin_amdgcn_mfma_f32_32x32x16_bf16(al.s, bh.s, acc, 0, 0, 0);
  }
  return acc;
}

__global__ __launch_bounds__(256) void expm_mfma_kernel(
    const float* __restrict__ flat, const float* __restrict__ q,
    const float* __restrict__ dtp, float* __restrict__ out_q,
    float* __restrict__ out_dlogp) {
  __shared__ unsigned int S[4][2][32][32];          // 32 KiB
  const int tid = threadIdx.x;
  const int w = tid >> 6, lane = tid & 63;
  const int C = lane & 31, G = lane >> 5;
  const int m = blockIdx.x * 4 + w;
  const float dt = dtp[0];
  unsigned int* s0 = &S[w][0][0][0];
  unsigned int* s1 = &S[w][1][0][0];

  // load A = dt*clip(dense) in D-layout; remember diag mask
  float A[16], dI[16];
  const float* fm = flat + (size_t)m * 1024;
  #pragma unroll
  for (int reg = 0; reg < 16; ++reg) {
    int rd = (reg & 3) + 8 * (reg >> 2) + 4 * G;
    float v = fm[rd * 32 + C];
    A[reg] = dt * fminf(fmaxf(v, -20.f), 20.f);
    dI[reg] = (rd == C) ? 1.0f : 0.0f;
  }

  // dlogp = trace(A)
  float tr = 0.f;
  #pragma unroll
  for (int reg = 0; reg < 16; ++reg) tr += dI[reg] * A[reg];
  #pragma unroll
  for (int off = 1; off < 64; off <<= 1) tr += __shfl_xor(tr, off);
  if (lane == 0) out_dlogp[m] = tr;

  // 1-norm = max column abs-sum (column == C per lane)
  float cs = 0.f;
  #pragma unroll
  for (int reg = 0; reg < 16; ++reg) cs += fabsf(A[reg]);
  cs += __shfl_xor(cs, 32);
  float nrm = cs;
  #pragma unroll
  for (int off = 1; off < 32; off <<= 1) nrm = fmaxf(nrm, __shfl_xor(nrm, off));

  int s = 0;
  if (nrm > 1.0f) {
    s = (int)ceilf(log2f(nrm));
    s = s < 0 ? 0 : (s > 12 ? 12 : s);
  }
  const float sc = exp2f(-(float)s);
  #pragma unroll
  for (int reg = 0; reg < 16; ++reg) A[reg] *= sc;

  f32x16 acc = {};

  // A^2
  stage_hl(A, s0, C, G);
  WAITLDS;
  acc = prod32(s0, s0, C, G, acc);
  float A2[16];
  #pragma unroll
  for (int i = 0; i < 16; ++i) A2[i] = acc[i];

  // A^3 = A2*A
  stage_hl(A2, s1, C, G);
  WAITLDS;
  f32x16 acc2 = {};
  acc2 = prod32(s1, s0, C, G, acc2);
  float Tmp[16];
  #pragma unroll
  for (int i = 0; i < 16; ++i) Tmp[i] = acc2[i];
  stage_hl(Tmp, s0, C, G);                          // s0 = A^3

  // C2 = I/720 + A/5040 + A2/40320
  #pragma unroll
  for (int i = 0; i < 16; ++i)
    Tmp[i] = (1.0f / 720.0f) * dI[i] + (1.0f / 5040.0f) * A[i] + (1.0f / 40320.0f) * A2[i];
  stage_hl(Tmp, s1, C, G);
  WAITLDS;
  f32x16 acc3 = {};
  acc3 = prod32(s1, s0, C, G, acc3);                // C2*A3

  // C1 + C2*A3, where C1 = I/6 + A/24 + A2/120
  #pragma unroll
  for (int i = 0; i < 16; ++i)
    Tmp[i] = acc3[i] + (1.0f / 6.0f) * dI[i] + (1.0f / 24.0f) * A[i] + (1.0f / 120.0f) * A2[i];
  stage_hl(Tmp, s1, C, G);
  WAITLDS;
  f32x16 acc4 = {};
  acc4 = prod32(s1, s0, C, G, acc4);                // (C1+C2*A3)*A3

  // E = I + A + A2/2 + (...)
  float E[16];
  #pragma unroll
  for (int i = 0; i < 16; ++i)
    E[i] = acc4[i] + dI[i] + A[i] + 0.5f * A2[i];

  // squarings (s wave-uniform)
  #pragma unroll 1
  for (int it = 0; it < s; ++it) {
    stage_hl(E, s1, C, G);
    WAITLDS;
    f32x16 accs = {};
    accs = prod32(s1, s1, C, G, accs);
    #pragma unroll
    for (int i = 0; i < 16; ++i) E[i] = accs[i];
  }

  // new_q = E*q : lane holds E[rd][C]; multiply by q[C], reduce across C
  float qv = q[(size_t)m * 32 + C];
  float pr[16];
  #pragma unroll
  for (int i = 0; i < 16; ++i) pr[i] = E[i] * qv;
  #pragma unroll
  for (int off = 1; off < 32; off <<= 1) {
    #pragma unroll
    for (int i = 0; i < 16; ++i) pr[i] += __shfl_xor(pr[i], off);
  }
  if (C == 0) {   // lanes 0 (G=0) and 32 (G=1) cover all 32 rows
    #pragma unroll
    for (int reg = 0; reg < 16; ++reg) {
      int rd = (reg & 3) + 8 * (reg >> 2) + 4 * G;
      out_q[(size_t)m * 32 + rd] = pr[reg];
    }
  }
}

extern "C" void kernel_launch(void* const* d_in, const int* in_sizes, int n_in,
                              void* d_out, int out_size, void* d_ws, size_t ws_size,
                              hipStream_t stream) {
  const float* q    = (const float*)d_in[0];
  const float* p    = (const float*)d_in[1];
  const float* t    = (const float*)d_in[2];
  const float* dt   = (const float*)d_in[3];
  const float* W0   = (const float*)d_in[4];
  const float* b0   = (const float*)d_in[5];
  const float* W1   = (const float*)d_in[6];
  const float* b1   = (const float*)d_in[7];
  const float* W2   = (const float*)d_in[8];
  const float* b2   = (const float*)d_in[9];
  const float* W3   = (const float*)d_in[10];
  const float* b3   = (const float*)d_in[11];
  const float* Wout = (const float*)d_in[12];
  const float* bout = (const float*)d_in[13];

  // ws layout
  float* flat = (float*)d_ws;                                   // B*1024 f32
  __hip_bfloat16* act1 = (__hip_bfloat16*)((char*)d_ws + (size_t)BTOT * 1024 * 4);
  __hip_bfloat16* act2 = act1 + (size_t)BTOT * 512;
  __hip_bfloat16* pbf  = act2 + (size_t)BTOT * 512;
  __hip_bfloat16* Wt0  = pbf + (size_t)BTOT * 32;
  __hip_bfloat16* Wt1  = Wt0 + 512 * 32;
  __hip_bfloat16* Wt2  = Wt1 + 512 * 512;
  __hip_bfloat16* Wt3  = Wt2 + 512 * 512;
  __hip_bfloat16* WtO  = Wt3 + 512 * 512;

  dim3 blk(256);
  convert_p_kernel<<<BTOT * 32 / 1024, blk, 0, stream>>>(p, pbf);
  transpose_w_kernel<<<dim3(1, 16),  blk, 0, stream>>>(W0,   Wt0, 32,  512);
  transpose_w_kernel<<<dim3(16, 16), blk, 0, stream>>>(W1,   Wt1, 512, 512);
  transpose_w_kernel<<<dim3(16, 16), blk, 0, stream>>>(W2,   Wt2, 512, 512);
  transpose_w_kernel<<<dim3(16, 16), blk, 0, stream>>>(W3,   Wt3, 512, 512);
  transpose_w_kernel<<<dim3(16, 32), blk, 0, stream>>>(Wout, WtO, 512, 1024);

  mlp_mfma_kernel<32, true, false><<<dim3(128, 4), blk, 0, stream>>>(
      pbf, 32, 32, t, Wt0, W0 + 32 * 512, b0, act1, 512);
  mlp_mfma_kernel<64, true, false><<<dim3(128, 4), blk, 0, stream>>>(
      act1, 512, 512, t, Wt1, W1 + 512 * 512, b1, act2, 512);
  mlp_mfma_kernel<64, true, false><<<dim3(128, 4), blk, 0, stream>>>(
      act2, 512, 512, t, Wt2, W2 + 512 * 512, b2, act1, 512);
  mlp_mfma_kernel<64, true, false><<<dim3(128, 4), blk, 0, stream>>>(
      act1, 512, 512, t, Wt3, W3 + 512 * 512, b3, act2, 512);
  mlp_mfma_kernel<64, false, true><<<dim3(128, 8), blk, 0, stream>>>(
      act2, 512, 512, t, WtO, Wout + 512 * 1024, bout, flat, 1024);

  float* out_q     = (float*)d_out;
  float* out_dlogp = out_q + (size_t)BTOT * 32;
  expm_mfma_kernel<<<BTOT / 4, blk, 0, stream>>>(flat, q, dt, out_q, out_dlogp);
}

// Round 6
// 163.832 us; speedup vs baseline: 14.0716x; 1.0128x over previous
//
#include <hip/hip_runtime.h>
#include <hip/hip_bf16.h>
#include <math.h>

#define BTOT 16384

typedef __attribute__((ext_vector_type(8))) short short8;
typedef __attribute__((ext_vector_type(4))) float f32x4;
typedef __attribute__((ext_vector_type(16))) float f32x16;

__device__ __forceinline__ float selu_f(float x) {
  const float scale = 1.0507009873554805f;
  const float alpha = 1.6732632423543772f;
  return scale * (x > 0.0f ? x : alpha * expm1f(x));
}

// ---------------- prep: p -> bf16 ----------------
__global__ __launch_bounds__(256) void convert_p_kernel(
    const float* __restrict__ p, __hip_bfloat16* __restrict__ out) {
  int i = (blockIdx.x * 256 + threadIdx.x) * 4;
  float4 v = *reinterpret_cast<const float4*>(p + i);
  out[i + 0] = __float2bfloat16(v.x);
  out[i + 1] = __float2bfloat16(v.y);
  out[i + 2] = __float2bfloat16(v.z);
  out[i + 3] = __float2bfloat16(v.w);
}

// ---------------- prep: W[K][N] f32 -> Wt[N][K] bf16 (t-row excluded) ---------
__global__ __launch_bounds__(256) void transpose_w_kernel(
    const float* __restrict__ W, __hip_bfloat16* __restrict__ Wt, int K, int N) {
  __shared__ float tile[32][33];
  const int kb = blockIdx.x * 32, nb = blockIdx.y * 32;
  const int tx = threadIdx.x & 31, ty = threadIdx.x >> 5;
  #pragma unroll
  for (int rr = 0; rr < 4; ++rr) {
    int kl = ty + rr * 8;
    tile[kl][tx] = W[(size_t)(kb + kl) * N + nb + tx];
  }
  __syncthreads();
  #pragma unroll
  for (int rr = 0; rr < 4; ++rr) {
    int nl = ty + rr * 8;
    Wt[(size_t)(nb + nl) * K + kb + tx] = __float2bfloat16(tile[tx][nl]);
  }
}

// ---------------- MFMA MLP layer ----------------
// MODE 0: selu + bf16 store (hidden).  MODE 1: clip(+-20) + bf16 store (final).
template<int BK, int MODE>
__global__ __launch_bounds__(256) void mlp_mfma_kernel(
    const __hip_bfloat16* __restrict__ X, int ldx, int Kc,
    const float* __restrict__ tvec,
    const __hip_bfloat16* __restrict__ Wt,    // [N][Kc] bf16
    const float* __restrict__ Wlast,          // t-row, fp32 [N]
    const float* __restrict__ bias,           // fp32 [N]
    __hip_bfloat16* __restrict__ Yout, int ldy) {
  constexpr int NBLK = BK / 8;
  constexpr int AB = 128 * BK * 2;
  constexpr int IPW = AB / 1024 / 4;
  __shared__ char lds[4 * AB];
  const int tid = threadIdx.x;
  const int w = tid >> 6, lane = tid & 63;
  const int wr = w >> 1, wc = w & 1;
  const int rowbase = blockIdx.x * 128, colbase = blockIdx.y * 128;

  const __hip_bfloat16* srcA[IPW];
  const __hip_bfloat16* srcB[IPW];
  int ldsoff[IPW];
  #pragma unroll
  for (int i = 0; i < IPW; ++i) {
    int f = (w * IPW + i) * 64 + lane;
    int r = f / NBLK, slot = f % NBLK;
    int kb = slot ^ (r & (NBLK - 1));
    srcA[i] = X + (size_t)(rowbase + r) * ldx + kb * 8;
    srcB[i] = Wt + (size_t)(colbase + r) * Kc + kb * 8;
    ldsoff[i] = (w * IPW + i) * 1024;
  }

  f32x4 acc[4][4] = {};

  int aoff[4], amask[4], boff[4], bmask[4];
  #pragma unroll
  for (int i = 0; i < 4; ++i) {
    int ra = wr * 64 + i * 16 + (lane & 15);
    aoff[i] = ra * BK * 2;
    amask[i] = ra & (NBLK - 1);
    int cb = wc * 64 + i * 16 + (lane & 15);
    boff[i] = cb * BK * 2;
    bmask[i] = cb & (NBLK - 1);
  }
  const int kgrp = lane >> 4;

  auto stage_tile = [&](int buf, int t) {
    char* ab = lds + buf * 2 * AB;
    #pragma unroll
    for (int i = 0; i < IPW; ++i) {
      __builtin_amdgcn_global_load_lds(
          (const __attribute__((address_space(1))) void*)(srcA[i] + t * BK),
          (__attribute__((address_space(3))) void*)(ab + ldsoff[i]), 16, 0, 0);
      __builtin_amdgcn_global_load_lds(
          (const __attribute__((address_space(1))) void*)(srcB[i] + t * BK),
          (__attribute__((address_space(3))) void*)(ab + AB + ldsoff[i]), 16, 0, 0);
    }
  };

  auto compute_tile = [&](int buf) {
    const char* Abse = lds + buf * 2 * AB;
    const char* Bbse = Abse + AB;
    #pragma unroll
    for (int kh = 0; kh < BK / 32; ++kh) {
      short8 a[4], b[4];
      const int kb = kh * 4 + kgrp;
      #pragma unroll
      for (int i = 0; i < 4; ++i) {
        a[i] = *reinterpret_cast<const short8*>(Abse + aoff[i] + ((kb ^ amask[i]) * 16));
        b[i] = *reinterpret_cast<const short8*>(Bbse + boff[i] + ((kb ^ bmask[i]) * 16));
      }
      #pragma unroll
      for (int i = 0; i < 4; ++i)
        #pragma unroll
        for (int j = 0; j < 4; ++j)
          acc[i][j] = __builtin_amdgcn_mfma_f32_16x16x32_bf16(a[i], b[j], acc[i][j], 0, 0, 0);
    }
  };

  const int nt = Kc / BK;
  stage_tile(0, 0);
  asm volatile("s_waitcnt vmcnt(0)" ::: "memory");
  __syncthreads();
  int buf = 0;
  #pragma unroll 1
  for (int t = 0; t < nt - 1; ++t) {
    stage_tile(buf ^ 1, t + 1);
    compute_tile(buf);
    asm volatile("s_waitcnt vmcnt(0)" ::: "memory");
    __syncthreads();
    buf ^= 1;
  }
  compute_tile(buf);

  const int colloc = lane & 15;
  const int rowgrp = lane >> 4;
  float wl[4], bb[4];
  #pragma unroll
  for (int j = 0; j < 4; ++j) {
    int col = colbase + wc * 64 + j * 16 + colloc;
    wl[j] = Wlast[col];
    bb[j] = bias[col];
  }
  #pragma unroll
  for (int i = 0; i < 4; ++i) {
    #pragma unroll
    for (int e = 0; e < 4; ++e) {
      int row = rowbase + wr * 64 + i * 16 + rowgrp * 4 + e;
      float tv = tvec[row];
      #pragma unroll
      for (int j = 0; j < 4; ++j) {
        float v = acc[i][j][e] + tv * wl[j] + bb[j];
        if (MODE == 0) v = selu_f(v);
        else           v = fminf(fmaxf(v, -20.f), 20.f);
        int col = colbase + wc * 64 + j * 16 + colloc;
        Yout[(size_t)row * ldy + col] = __float2bfloat16(v);
      }
    }
  }
}

// ---------------- expm: dual-layout single-bf16 MFMA + matvec squaring -------
// One 32x32 matrix per 64-lane wave. f32 state in 32x32x16 D-layout regs:
// lane (C=lane&31, G=lane>>5) holds M[rd][C], rd(reg)=(reg&3)+8*(reg>>2)+4G.
// LDS slabs per wave (512 dwords each):
//  RS row-pair slab: RS[RIDX(kp,r)] = u32(bf16 X[r][2kp] | bf16 X[r][2kp+1]<<16)
//  CS col-pair slab: CS[CIDX(c,kp)] = u32(bf16 Y[2kp][c] | bf16 Y[2kp+1][c]<<16)
// Product X*Y: A-frag = 8 conflict-free b32 reads from RS (perm-free: memory
// row-pairs ARE the operand format), B-frag = 2 uint4 reads from CS, 2 MFMA.
// A/B share the same (h,G,e)->k bijection => layout-robust (round-4/5 argument).
// All raw (unscaled) products; u = dt*2^-s folded into PS coefficients.
// E^(2^s) q computed as 2^s exact f32 mat-vecs (no squaring quantization).
#define WAITLDS asm volatile("s_waitcnt lgkmcnt(0)" ::: "memory")
#define RIDX(kp, r) ((kp) * 32 + ((r) ^ (kp)))
#define CIDX(c, kp) ((c) * 16 + ((kp) ^ ((((c) >> 1) & 3) << 2)))

__device__ __forceinline__ unsigned int bf16r(float x) {
  return (__float_as_uint(x) + 0x8000u) >> 16;   // round-half-up bf16
}

__device__ __forceinline__ void prodRC(const unsigned int* __restrict__ RS,
                                       const unsigned int* __restrict__ CS,
                                       int C, int G, float (&D)[16]) {
  f32x16 acc = {};
  #pragma unroll
  for (int h = 0; h < 2; ++h) {
    const int kp0 = 8 * h + 4 * G;
    union { short8 s8; unsigned int u[4]; } a, b;
    #pragma unroll
    for (int i = 0; i < 4; ++i) a.u[i] = RS[RIDX(kp0 + i, C)];
    uint4 bv = *reinterpret_cast<const uint4*>(&CS[CIDX(C, kp0)]);
    b.u[0] = bv.x; b.u[1] = bv.y; b.u[2] = bv.z; b.u[3] = bv.w;
    acc = __builtin_amdgcn_mfma_f32_32x32x16_bf16(a.s8, b.s8, acc, 0, 0, 0);
  }
  #pragma unroll
  for (int i = 0; i < 16; ++i) D[i] = acc[i];
}

// D-layout regs -> row-pair slab (cross-lane pairing of adjacent columns)
__device__ __forceinline__ void stage_row(const float (&X)[16],
                                          unsigned int* __restrict__ RS,
                                          int C, int G) {
  unsigned int pw[16];
  #pragma unroll
  for (int reg = 0; reg < 16; ++reg) {
    float o = __shfl_xor(X[reg], 1);
    unsigned int uo = bf16r(X[reg]), up = bf16r(o);
    pw[reg] = (C & 1) ? ((uo << 16) | up) : ((up << 16) | uo);
  }
  const int kp = C >> 1;
  if ((C & 1) == 0) {
    #pragma unroll
    for (int reg = 0; reg < 8; ++reg)
      RS[RIDX(kp, (reg & 3) + 8 * (reg >> 2) + 4 * G)] = pw[reg];
  } else {
    #pragma unroll
    for (int reg = 8; reg < 16; ++reg)
      RS[RIDX(kp, (reg & 3) + 8 * (reg >> 2) + 4 * G)] = pw[reg];
  }
}

// D-layout regs -> col-pair slab (in-lane: adjacent rows are adjacent regs)
__device__ __forceinline__ void stage_col(const float (&X)[16],
                                          unsigned int* __restrict__ CS,
                                          int C, int G) {
  #pragma unroll
  for (int j = 0; j < 8; ++j) {
    int rd0 = ((2 * j) & 3) + 8 * ((2 * j) >> 2) + 4 * G;   // even
    CS[CIDX(C, rd0 >> 1)] = bf16r(X[2 * j]) | (bf16r(X[2 * j + 1]) << 16);
  }
}

__global__ __launch_bounds__(256) void expm_mfma2_kernel(
    const __hip_bfloat16* __restrict__ flat,  // [B,1024] bf16, pre-clipped
    const float* __restrict__ q,
    const float* __restrict__ dtp,
    float* __restrict__ out_q,
    float* __restrict__ out_dlogp) {
  __shared__ __align__(16) unsigned int SL[4][2][512];   // 16 KiB
  const int tid = threadIdx.x;
  const int w = tid >> 6, lane = tid & 63;
  const int C = lane & 31, G = lane >> 5;
  const int m = blockIdx.x * 4 + w;
  const float dt = dtp[0];
  unsigned int* RS = &SL[w][0][0];
  unsigned int* CS = &SL[w][1][0];

  // coalesced raw load: lane covers rows (l>>2) and 16+(l>>2), cols (l&3)*8..+8
  const uint4* fm = reinterpret_cast<const uint4*>(flat + (size_t)m * 1024);
  uint4 v0 = fm[lane];
  uint4 v1 = fm[lane + 64];

  // inf-norm of raw matrix (max row abs-sum); any submultiplicative norm works
  float sa = 0.f, sb = 0.f;
  {
    unsigned int a0[4] = {v0.x, v0.y, v0.z, v0.w};
    unsigned int a1[4] = {v1.x, v1.y, v1.z, v1.w};
    #pragma unroll
    for (int i = 0; i < 4; ++i) {
      sa += fabsf(__uint_as_float(a0[i] << 16)) + fabsf(__uint_as_float(a0[i] & 0xFFFF0000u));
      sb += fabsf(__uint_as_float(a1[i] << 16)) + fabsf(__uint_as_float(a1[i] & 0xFFFF0000u));
    }
  }
  sa += __shfl_xor(sa, 1); sa += __shfl_xor(sa, 2);
  sb += __shfl_xor(sb, 1); sb += __shfl_xor(sb, 2);
  float nrm = fmaxf(sa, sb);
  #pragma unroll
  for (int off = 4; off < 64; off <<= 1) nrm = fmaxf(nrm, __shfl_xor(nrm, off));

  int s = 0;
  float anrm = dt * nrm;
  if (anrm > 1.5f) {
    s = (int)ceilf(log2f(anrm * (1.0f / 1.5f)));
    s = s < 1 ? 1 : (s > 6 ? 6 : s);
  }
  const float u = dt * exp2f(-(float)s);
  const float u2 = u * u, u3 = u2 * u;

  // stage raw A row-pairs (verbatim: memory layout IS the packed format)
  {
    const int r0 = lane >> 2, kpb = (lane & 3) * 4;
    RS[RIDX(kpb + 0, r0)] = v0.x; RS[RIDX(kpb + 1, r0)] = v0.y;
    RS[RIDX(kpb + 2, r0)] = v0.z; RS[RIDX(kpb + 3, r0)] = v0.w;
    RS[RIDX(kpb + 0, r0 + 16)] = v1.x; RS[RIDX(kpb + 1, r0 + 16)] = v1.y;
    RS[RIDX(kpb + 2, r0 + 16)] = v1.z; RS[RIDX(kpb + 3, r0 + 16)] = v1.w;
  }
  WAITLDS;

  // D-layout A regs (f32) + raw u16s for col staging
  unsigned int hu[16];
  float A[16];
  #pragma unroll
  for (int reg = 0; reg < 16; ++reg) {
    int rd = (reg & 3) + 8 * (reg >> 2) + 4 * G;
    unsigned int ww = RS[RIDX(C >> 1, rd)];
    unsigned int h16 = (C & 1) ? (ww >> 16) : (ww & 0xFFFFu);
    hu[reg] = h16;
    A[reg] = __uint_as_float(h16 << 16);
  }

  // dlogp = dt * trace(raw)
  {
    float tr = 0.f;
    #pragma unroll
    for (int reg = 0; reg < 16; ++reg)
      tr += (((reg & 3) + 8 * (reg >> 2) + 4 * G) == C) ? A[reg] : 0.f;
    #pragma unroll
    for (int off = 1; off < 64; off <<= 1) tr += __shfl_xor(tr, off);
    if (lane == 0) out_dlogp[m] = dt * tr;
  }

  // stage raw A col-pairs (in-lane from the u16s)
  #pragma unroll
  for (int j = 0; j < 8; ++j) {
    int rd0 = ((2 * j) & 3) + 8 * ((2 * j) >> 2) + 4 * G;
    CS[CIDX(C, rd0 >> 1)] = hu[2 * j] | (hu[2 * j + 1] << 16);
  }
  WAITLDS;

  // raw product chain (Paterson-Stockmeyer order-8, u folded into coeffs)
  float T2[16]; prodRC(RS, CS, C, G, T2);        // A*A  (exact: bf16 inputs)
  stage_row(T2, RS, C, G); WAITLDS;
  float T3[16]; prodRC(RS, CS, C, G, T3);        // T2*A
  stage_col(T3, CS, C, G);                       // A-col dead -> reuse

  float Tm[16];
  #pragma unroll
  for (int i = 0; i < 16; ++i) {                 // C2 = I/720 + uA/5040 + u2T2/40320
    float dI = (((i & 3) + 8 * (i >> 2) + 4 * G) == C) ? 1.f : 0.f;
    Tm[i] = (1.0f / 720.0f) * dI + (u / 5040.0f) * A[i] + (u2 / 40320.0f) * T2[i];
  }
  stage_row(Tm, RS, C, G); WAITLDS;              // covers T3-col too
  float Z1[16]; prodRC(RS, CS, C, G, Z1);        // C2*T3

  #pragma unroll
  for (int i = 0; i < 16; ++i) {                 // W = C1 + u3*Z1
    float dI = (((i & 3) + 8 * (i >> 2) + 4 * G) == C) ? 1.f : 0.f;
    Tm[i] = (1.0f / 6.0f) * dI + (u / 24.0f) * A[i] + (u2 / 120.0f) * T2[i] + u3 * Z1[i];
  }
  stage_row(Tm, RS, C, G); WAITLDS;
  float Z2[16]; prodRC(RS, CS, C, G, Z2);        // W*T3

  float E[16];
  #pragma unroll
  for (int i = 0; i < 16; ++i) {                 // E = I + uA + u2T2/2 + u3Z2
    float dI = (((i & 3) + 8 * (i >> 2) + 4 * G) == C) ? 1.f : 0.f;
    E[i] = dI + u * A[i] + 0.5f * u2 * T2[i] + u3 * Z2[i];
  }

  // E^(2^s) q via 2^s exact f32 mat-vecs (E stays in registers)
  float qv = q[(size_t)m * 32 + C];
  const int nv = 1 << s;
  #pragma unroll 1
  for (int it = 0; it < nv; ++it) {
    float pr[16];
    #pragma unroll
    for (int i = 0; i < 16; ++i) pr[i] = E[i] * qv;
    #pragma unroll
    for (int off = 1; off < 32; off <<= 1) {
      #pragma unroll
      for (int i = 0; i < 16; ++i) pr[i] += __shfl_xor(pr[i], off);
    }
    float sel = 0.f;
    #pragma unroll
    for (int i = 0; i < 16; ++i)
      sel += ((((i & 3) + 8 * (i >> 2) + 4 * G) == C) ? pr[i] : 0.f);
    qv = sel + __shfl_xor(sel, 32);
  }
  if (G == 0) out_q[(size_t)m * 32 + C] = qv;
}

extern "C" void kernel_launch(void* const* d_in, const int* in_sizes, int n_in,
                              void* d_out, int out_size, void* d_ws, size_t ws_size,
                              hipStream_t stream) {
  const float* q    = (const float*)d_in[0];
  const float* p    = (const float*)d_in[1];
  const float* t    = (const float*)d_in[2];
  const float* dt   = (const float*)d_in[3];
  const float* W0   = (const float*)d_in[4];
  const float* b0   = (const float*)d_in[5];
  const float* W1   = (const float*)d_in[6];
  const float* b1   = (const float*)d_in[7];
  const float* W2   = (const float*)d_in[8];
  const float* b2   = (const float*)d_in[9];
  const float* W3   = (const float*)d_in[10];
  const float* b3   = (const float*)d_in[11];
  const float* Wout = (const float*)d_in[12];
  const float* bout = (const float*)d_in[13];

  // ws layout (all bf16 activations)
  __hip_bfloat16* flatb = (__hip_bfloat16*)d_ws;                 // B*1024
  __hip_bfloat16* act1  = flatb + (size_t)BTOT * 1024;           // B*512
  __hip_bfloat16* act2  = act1 + (size_t)BTOT * 512;             // B*512
  __hip_bfloat16* pbf   = act2 + (size_t)BTOT * 512;             // B*32
  __hip_bfloat16* Wt0   = pbf + (size_t)BTOT * 32;
  __hip_bfloat16* Wt1   = Wt0 + 512 * 32;
  __hip_bfloat16* Wt2   = Wt1 + 512 * 512;
  __hip_bfloat16* Wt3   = Wt2 + 512 * 512;
  __hip_bfloat16* WtO   = Wt3 + 512 * 512;

  dim3 blk(256);
  convert_p_kernel<<<BTOT * 32 / 1024, blk, 0, stream>>>(p, pbf);
  transpose_w_kernel<<<dim3(1, 16),  blk, 0, stream>>>(W0,   Wt0, 32,  512);
  transpose_w_kernel<<<dim3(16, 16), blk, 0, stream>>>(W1,   Wt1, 512, 512);
  transpose_w_kernel<<<dim3(16, 16), blk, 0, stream>>>(W2,   Wt2, 512, 512);
  transpose_w_kernel<<<dim3(16, 16), blk, 0, stream>>>(W3,   Wt3, 512, 512);
  transpose_w_kernel<<<dim3(16, 32), blk, 0, stream>>>(Wout, WtO, 512, 1024);

  mlp_mfma_kernel<32, 0><<<dim3(128, 4), blk, 0, stream>>>(
      pbf, 32, 32, t, Wt0, W0 + 32 * 512, b0, act1, 512);
  mlp_mfma_kernel<64, 0><<<dim3(128, 4), blk, 0, stream>>>(
      act1, 512, 512, t, Wt1, W1 + 512 * 512, b1, act2, 512);
  mlp_mfma_kernel<64, 0><<<dim3(128, 4), blk, 0, stream>>>(
      act2, 512, 512, t, Wt2, W2 + 512 * 512, b2, act1, 512);
  mlp_mfma_kernel<64, 0><<<dim3(128, 4), blk, 0, stream>>>(
      act1, 512, 512, t, Wt3, W3 + 512 * 512, b3, act2, 512);
  mlp_mfma_kernel<64, 1><<<dim3(128, 8), blk, 0, stream>>>(
      act2, 512, 512, t, WtO, Wout + 512 * 1024, bout, flatb, 1024);

  float* out_q     = (float*)d_out;
  float* out_dlogp = out_q + (size_t)BTOT * 32;
  expm_mfma2_kernel<<<BTOT / 4, blk, 0, stream>>>(flatb, q, dt, out_q, out_dlogp);
}